// Round 1
// baseline (570.060 us; speedup 1.0000x reference)
//
#include <hip/hip_runtime.h>
#include <hip/hip_bf16.h>
#include <math.h>

// VQEmbeddingGSSoft fused kernel for MI355X (gfx950).
// B=32, C=D=64, T=4096, M=512, temperature=0.5.
// Outputs: quantized (B,T,64) [8388608 floats], KL [1], perplexity [1].
//
// Algebra:
//  - softmax over M is shift-invariant, so l_m = 2*x.w_m - ||w_m||^2
//    (the ||x||^2 term cancels and is never computed).
//  - fixed safe bias instead of max-pass: s = exp(2l + 2g - 36) with
//    g = -log(-log u) <= 16.64, |l| <= ~0.3 -> never overflows in fp32.
//  - transcendental elimination: s = (e^l / log u)^2 * e^-36, reusing
//    e^l (needed for the KL softmax stats). One exp + one log per element.
//  - softmax normalization (1/Z per t) is deferred to the GEMM2 epilogue:
//    the MFMA C-layout keeps each lane's outputs at a single t.
//
// R1 fix: the GEMM1 loop was "#pragma unroll 4" -> partial unroll leaves i
// runtime -> spk[2*i] runtime-indexed -> the WHOLE spk array demoted to
// scratch (VGPR_Count=32, WRITE_SIZE showed +134 MB = 2048*256*256B spill).
// Full unroll makes every spk index compile-time so spk stays in VGPRs.

#define LOG_M   6.2383246250395075f   // ln(512)
#define EXPM36  2.3195228e-16f        // e^-36

typedef __attribute__((ext_vector_type(8))) __bf16 bf16x8;
typedef __attribute__((ext_vector_type(4))) float  floatx4;

__device__ __forceinline__ unsigned int f2bf_bits(float f) {
    unsigned int b = __builtin_bit_cast(unsigned int, f);
    return (b + 0x7fffu + ((b >> 16) & 1u)) >> 16;   // RNE bf16
}
__device__ __forceinline__ float bf2f(unsigned int bits16) {
    return __builtin_bit_cast(float, bits16 << 16);
}

// ---------------- prep: W fp32 -> bf16 (row-major + transposed) + ||w||^2 ----
__global__ void vq_prep(const float* __restrict__ W,
                        unsigned short* __restrict__ Wbf,
                        unsigned short* __restrict__ WTbf,
                        float* __restrict__ wn2)
{
    const int m = blockIdx.x * 256 + threadIdx.x;   // 0..511
    float acc = 0.f;
    #pragma unroll 8
    for (int d = 0; d < 64; ++d) {
        float v = W[m * 64 + d];
        acc = fmaf(v, v, acc);
        unsigned short h = (unsigned short)f2bf_bits(v);
        Wbf[m * 64 + d]  = h;
        WTbf[d * 512 + m] = h;
    }
    wn2[m] = acc;
}

// ---------------- main fused kernel ----------------
// grid = 2048 blocks (32 b * 64 t-tiles of 64), block = 256 (4 waves).
// Wave w handles 16 t-values (t0+16w .. +16) x all 512 codes.
// launch_bounds(256,3): cap ~168 VGPR, 12 waves/CU; spk[64] (statically
// indexed, full unroll) + ~60 temps must stay in registers -> no spill.
__global__ __launch_bounds__(256, 3) void vq_main(
    const float* __restrict__ x, const float* __restrict__ u,
    const unsigned short* __restrict__ Wbf, const unsigned short* __restrict__ WTbf,
    const float* __restrict__ wn2, float* __restrict__ out,
    float* __restrict__ avg_g, float* __restrict__ kl_g)
{
    __shared__ __align__(16) unsigned short xs[64][72];     // x tile, bf16, [t][d], padded
    __shared__ __align__(16) unsigned short sbuf[4][16][40];// per-wave S chunk [t][32m], padded
    __shared__ float avg_lds[512];

    const int tid  = threadIdx.x;
    const int bid  = blockIdx.x;
    const int b    = bid >> 6;
    const int t0   = (bid & 63) << 6;
    const int w    = tid >> 6;
    const int lane = tid & 63;
    const int ln   = lane & 15;   // n index (t within wave tile)
    const int q    = lane >> 4;   // quad

    avg_lds[tid]       = 0.0f;
    avg_lds[tid + 256] = 0.0f;

    // stage x tile: xs[t][d] = bf16(x[b][d][t0+t])  (coalesced along t)
    #pragma unroll
    for (int k2 = 0; k2 < 16; ++k2) {
        int idx = k2 * 256 + tid;
        int d = idx >> 6, t = idx & 63;
        float v = x[((size_t)(b * 64 + d)) * 4096 + (size_t)(t0 + t)];
        xs[t][d] = (unsigned short)f2bf_bits(v);
    }
    __syncthreads();

    const int tg = t0 + 16 * w + ln;   // this lane's global t

    // B-frag of GEMM1 (x tile): B[k=d=q*8+j][n=t=ln]
    bf16x8 xb0 = *(const bf16x8*)&xs[16 * w + ln][q * 8];
    bf16x8 xb1 = *(const bf16x8*)&xs[16 * w + ln][32 + q * 8];

    // ---- fused: logits (MFMA) + u load + gumbel + unnormalized sample ----
    unsigned int spk[64];   // 128 samples / lane, packed 2x bf16 (unnormalized)
    float T1 = 0.f, T2 = 0.f, Zg = 0.f;
    const float* ub = u + ((size_t)(b * 4096 + tg)) * 512 + 4 * q;

    #pragma unroll   // FULL unroll: spk indices must be compile-time (no scratch)
    for (int i = 0; i < 32; ++i) {
        // A-frag: W rows m = 16*i + ln, k = d = q*8+j
        const unsigned short* wrow = Wbf + (size_t)(16 * i + ln) * 64 + q * 8;
        bf16x8 a0 = *(const bf16x8*)(wrow);
        bf16x8 a1 = *(const bf16x8*)(wrow + 32);
        float4 uv = *(const float4*)(ub + 16 * i);
        const float4 wv = *(const float4*)(wn2 + 16 * i + 4 * q);

        floatx4 acc = 0.0f;
        acc = __builtin_amdgcn_mfma_f32_16x16x32_bf16(a0, xb0, acc, 0, 0, 0);
        acc = __builtin_amdgcn_mfma_f32_16x16x32_bf16(a1, xb1, acc, 0, 0, 0);
        // C/D layout: n = ln (t), m = 16*i + 4*q + r

        float sr[4];
        const float ua[4] = {uv.x, uv.y, uv.z, uv.w};
        const float wa[4] = {wv.x, wv.y, wv.z, wv.w};
        #pragma unroll
        for (int r = 0; r < 4; ++r) {
            float l = fmaf(2.0f, acc[r], -wa[r]);
            float e = __expf(l);
            T1 += e;
            T2 = fmaf(l, e, T2);
            float uu = fmaxf(ua[r], 1e-9f);
            // inner log: accurate near 1 via log1p poly (|z|<=0.25), HW log otherwise
            float z = uu - 1.0f;
            float p = fmaf(z, -0.125f, 0.14285715f);
            p = fmaf(z, p, -0.16666667f);
            p = fmaf(z, p, 0.2f);
            p = fmaf(z, p, -0.25f);
            p = fmaf(z, p, 0.33333334f);
            p = fmaf(z, p, -0.5f);
            p = fmaf(z, p, 1.0f);
            float il = (uu > 0.75f) ? (z * p) : __logf(uu);   // log(u) < 0
            float rr = e * __builtin_amdgcn_rcpf(il);          // e^l / log(u)
            float s = (rr * rr) * EXPM36;                      // exp(2l + 2g - 36)
            Zg += s;
            sr[r] = s;
        }
        spk[2 * i]     = f2bf_bits(sr[0]) | (f2bf_bits(sr[1]) << 16);
        spk[2 * i + 1] = f2bf_bits(sr[2]) | (f2bf_bits(sr[3]) << 16);
    }

    // codes for a given t live in lanes {t, t+16, t+32, t+48}
    T1 += __shfl_xor(T1, 16); T1 += __shfl_xor(T1, 32);
    T2 += __shfl_xor(T2, 16); T2 += __shfl_xor(T2, 32);
    Zg += __shfl_xor(Zg, 16); Zg += __shfl_xor(Zg, 32);

    // KL(t) = sum_m p*(logp + logM) = T2/T1 - ln(T1) + ln(M)  (accurate logf)
    float klw = T2 / T1 - logf(T1) + LOG_M;
    klw += __shfl_xor(klw, 1);  klw += __shfl_xor(klw, 2);
    klw += __shfl_xor(klw, 4);  klw += __shfl_xor(klw, 8);
    klw += __shfl_xor(klw, 16); klw += __shfl_xor(klw, 32);
    if (lane == 0) atomicAdd(kl_g, 0.25f * klw);   // each t counted 4x (quad dup)

    const float invZ = 1.0f / Zg;   // per-t (all quads of this t agree)

    // ---- GEMM2: Q^T[d][t] = W^T @ S_un, K=512 in 16 chunks of 32 ----
    floatx4 C2[4];
    #pragma unroll
    for (int dt = 0; dt < 4; ++dt) C2[dt] = 0.0f;

    #pragma unroll
    for (int kk = 0; kk < 16; ++kk) {
        #pragma unroll
        for (int ii = 0; ii < 2; ++ii) {
            const int i = 2 * kk + ii;   // m = 16*i + 4*q + r
            uint2 pk;
            pk.x = spk[2 * i];
            pk.y = spk[2 * i + 1];
            // stage bf16 samples into wave-private LDS: sbuf[t][m-32kk]
            *(uint2*)&sbuf[w][ln][16 * ii + 4 * q] = pk;
            // avg_probs contribution (normalized): reduce over this wave's 16 t's
            float v0 = bf2f(pk.x & 0xffffu) * invZ;
            float v1 = bf2f(pk.x >> 16)     * invZ;
            float v2 = bf2f(pk.y & 0xffffu) * invZ;
            float v3 = bf2f(pk.y >> 16)     * invZ;
            v0 += __shfl_xor(v0,1); v0 += __shfl_xor(v0,2); v0 += __shfl_xor(v0,4); v0 += __shfl_xor(v0,8);
            v1 += __shfl_xor(v1,1); v1 += __shfl_xor(v1,2); v1 += __shfl_xor(v1,4); v1 += __shfl_xor(v1,8);
            v2 += __shfl_xor(v2,1); v2 += __shfl_xor(v2,2); v2 += __shfl_xor(v2,4); v2 += __shfl_xor(v2,8);
            v3 += __shfl_xor(v3,1); v3 += __shfl_xor(v3,2); v3 += __shfl_xor(v3,4); v3 += __shfl_xor(v3,8);
            if (ln == 0) {
                atomicAdd(&avg_lds[16*i + 4*q + 0], v0);
                atomicAdd(&avg_lds[16*i + 4*q + 1], v1);
                atomicAdd(&avg_lds[16*i + 4*q + 2], v2);
                atomicAdd(&avg_lds[16*i + 4*q + 3], v3);
            }
        }
        // cross-lane LDS RAW within the wave: drain DS queue before frag read
        __asm__ volatile("s_waitcnt lgkmcnt(0)" ::: "memory");
        // B-frag: B[k = q*8+j][n = ln] = S[32kk + q*8+j][t]
        bf16x8 sb = *(const bf16x8*)&sbuf[w][ln][8 * q];
        #pragma unroll
        for (int dt = 0; dt < 4; ++dt) {
            // A-frag: A[d = 16dt+ln][k = 32kk + q*8+j] = W^T (m-contiguous)
            bf16x8 a = *(const bf16x8*)(WTbf + (size_t)(16 * dt + ln) * 512 + 32 * kk + 8 * q);
            C2[dt] = __builtin_amdgcn_mfma_f32_16x16x32_bf16(a, sb, C2[dt], 0, 0, 0);
        }
    }

    // ---- epilogue: normalize (per-t invZ) and store quantized ----
    // lane holds d = 16*dt + 4*q + r at its t
    float* op = out + ((size_t)(b * 4096 + tg)) * 64 + 4 * q;
    #pragma unroll
    for (int dt = 0; dt < 4; ++dt) {
        floatx4 c = C2[dt];
        c[0] *= invZ; c[1] *= invZ; c[2] *= invZ; c[3] *= invZ;
        *(floatx4*)(op + 16 * dt) = c;
    }

    __syncthreads();
    atomicAdd(&avg_g[tid],       avg_lds[tid]);
    atomicAdd(&avg_g[tid + 256], avg_lds[tid + 256]);
}

// ---------------- finalize: KL mean + perplexity ----------------
__global__ void vq_fin(const float* __restrict__ avg_g, const float* __restrict__ kl_g,
                       float* __restrict__ out)
{
    const int lane = threadIdx.x;   // 64 threads
    float acc = 0.f;
    #pragma unroll
    for (int k = 0; k < 8; ++k) {
        float a = avg_g[lane * 8 + k] * (1.0f / 131072.0f);
        acc += a * logf(a + 1e-10f);
    }
    acc += __shfl_xor(acc, 1);  acc += __shfl_xor(acc, 2);
    acc += __shfl_xor(acc, 4);  acc += __shfl_xor(acc, 8);
    acc += __shfl_xor(acc, 16); acc += __shfl_xor(acc, 32);
    if (lane == 0) {
        out[8388608] = kl_g[0] * (1.0f / 32.0f);   // mean over B
        out[8388609] = expf(-acc);
    }
}

extern "C" void kernel_launch(void* const* d_in, const int* in_sizes, int n_in,
                              void* d_out, int out_size, void* d_ws, size_t ws_size,
                              hipStream_t stream)
{
    const float* x = (const float*)d_in[0];   // (32, 64, 4096)
    const float* u = (const float*)d_in[1];   // (32, 4096, 512)
    const float* W = (const float*)d_in[2];   // (512, 64)
    float* out = (float*)d_out;

    char* ws = (char*)d_ws;
    unsigned short* Wbf  = (unsigned short*)(ws);            // 65536 B
    unsigned short* WTbf = (unsigned short*)(ws + 65536);    // 65536 B
    float* wn2   = (float*)(ws + 131072);                    // 2048 B
    float* avg_g = (float*)(ws + 133120);                    // 2048 B
    float* kl_g  = (float*)(ws + 135168);                    // 4 B

    // zero the accumulators (ws is poisoned to 0xAA before every launch)
    (void)hipMemsetAsync(ws + 133120, 0, 2048 + 64, stream);

    vq_prep<<<dim3(2),    dim3(256), 0, stream>>>(W, Wbf, WTbf, wn2);
    vq_main<<<dim3(2048), dim3(256), 0, stream>>>(x, u, Wbf, WTbf, wn2, out, avg_g, kl_g);
    vq_fin <<<dim3(1),    dim3(64),  0, stream>>>(avg_g, kl_g, out);
}

// Round 2
// 504.083 us; speedup vs baseline: 1.1309x; 1.1309x over previous
//
#include <hip/hip_runtime.h>
#include <hip/hip_bf16.h>
#include <math.h>

// VQEmbeddingGSSoft fused kernels for MI355X (gfx950).
// B=32, C=D=64, T=4096, M=512, temperature=0.5.
// Outputs: quantized (B,T,64) [8388608 floats], KL [1], perplexity [1].
//
// R2 structure: the spk[64] register array (samples held between GEMM1 and
// GEMM2) forced ~168 regs/lane -> 30% occupancy -> latency-bound (R1: VALU
// 29%, MfmaUtil 2.4%, HBM 9%). Split into two high-occupancy streaming
// kernels with S staged in global memory (134 MB bf16, fits L3):
//   vq_samp: logits MFMA + gumbel + Z/KL; writes S in GEMM2's B-frag layout
//            (coalesced 1KB/wave stores) + invZ per t.
//   vq_qnt : reads S fragments back, GEMM2 + avg_probs (DPP butterfly
//            reductions on VALU pipe instead of 512 ds_swizzle/wave) +
//            16-way-shadowed global atomics.
// Falls back to the verified R1 single-kernel path if ws_size < 129 MiB.

#define LOG_M   6.2383246250395075f   // ln(512)
#define EXPM36  2.3195228e-16f        // e^-36

typedef __attribute__((ext_vector_type(8))) __bf16 bf16x8;
typedef __attribute__((ext_vector_type(4))) float  floatx4;

__device__ __forceinline__ unsigned int f2bf_bits(float f) {
    unsigned int b = __builtin_bit_cast(unsigned int, f);
    return (b + 0x7fffu + ((b >> 16) & 1u)) >> 16;   // RNE bf16
}
__device__ __forceinline__ float bf2f(unsigned int bits16) {
    return __builtin_bit_cast(float, bits16 << 16);
}
// DPP add: v += lane-permuted v (VALU pipe, no DS traffic)
template <int CTRL>
__device__ __forceinline__ float dpp_add(float v) {
    int t = __builtin_amdgcn_update_dpp(0, __builtin_bit_cast(int, v),
                                        CTRL, 0xF, 0xF, true);
    return v + __builtin_bit_cast(float, t);
}
// full reduction over the 16-lane row (ln axis): xor1, xor2, ror4, ror8
__device__ __forceinline__ float row16_sum(float v) {
    v = dpp_add<0xB1>(v);    // quad_perm [1,0,3,2]  (xor 1)
    v = dpp_add<0x4E>(v);    // quad_perm [2,3,0,1]  (xor 2)
    v = dpp_add<0x124>(v);   // row_ror:4
    v = dpp_add<0x128>(v);   // row_ror:8
    return v;
}

// ---------------- prep: W fp32 -> bf16 (row-major + transposed) + ||w||^2 ----
// zero_mode=1: also zero the shadow accumulators (split path, replaces memset)
__global__ void vq_prep(const float* __restrict__ W,
                        unsigned short* __restrict__ Wbf,
                        unsigned short* __restrict__ WTbf,
                        float* __restrict__ wn2,
                        float* __restrict__ avg_sh,   // [16][512]
                        float* __restrict__ kl_sh,    // [16*64]
                        int zero_mode)
{
    const int m = blockIdx.x * 256 + threadIdx.x;   // 0..511
    float acc = 0.f;
    #pragma unroll 8
    for (int d = 0; d < 64; ++d) {
        float v = W[m * 64 + d];
        acc = fmaf(v, v, acc);
        unsigned short h = (unsigned short)f2bf_bits(v);
        Wbf[m * 64 + d]  = h;
        WTbf[d * 512 + m] = h;
    }
    wn2[m] = acc;
    if (zero_mode) {
        #pragma unroll
        for (int j = 0; j < 16; ++j) avg_sh[m * 16 + j] = 0.f;
        kl_sh[m * 2]     = 0.f;
        kl_sh[m * 2 + 1] = 0.f;
    }
}

// ---------------- K1: sample generation (streaming, high occupancy) --------
// grid = 2048 (b, t-tile of 64), block = 256 (4 waves), wave w -> 16 t's.
// Writes S (unnormalized bf16 samples) in GEMM2 B-frag layout:
//   Sblk[((bid*16 + kk)*4 + w)*512 + lane*8 .. +7]  (16B/lane, 1KB/wave store)
// and invZ[b*4096 + t].
__global__ __launch_bounds__(256, 4) void vq_samp(
    const float* __restrict__ x, const float* __restrict__ u,
    const unsigned short* __restrict__ Wbf,
    const float* __restrict__ wn2,
    unsigned short* __restrict__ Sblk,
    float* __restrict__ invZg,
    float* __restrict__ kl_sh)
{
    __shared__ __align__(16) unsigned short xs[64][72];      // x tile [t][d]
    __shared__ __align__(16) unsigned short sbuf[4][16][40]; // per-wave transpose buf

    const int tid  = threadIdx.x;
    const int bid  = blockIdx.x;
    const int b    = bid >> 6;
    const int t0   = (bid & 63) << 6;
    const int w    = tid >> 6;
    const int lane = tid & 63;
    const int ln   = lane & 15;
    const int q    = lane >> 4;

    // stage x tile: xs[t][d] = bf16(x[b][d][t0+t])  (coalesced along t)
    #pragma unroll
    for (int k2 = 0; k2 < 16; ++k2) {
        int idx = k2 * 256 + tid;
        int d = idx >> 6, t = idx & 63;
        float v = x[((size_t)(b * 64 + d)) * 4096 + (size_t)(t0 + t)];
        xs[t][d] = (unsigned short)f2bf_bits(v);
    }
    __syncthreads();

    const int tg = t0 + 16 * w + ln;

    bf16x8 xb0 = *(const bf16x8*)&xs[16 * w + ln][q * 8];
    bf16x8 xb1 = *(const bf16x8*)&xs[16 * w + ln][32 + q * 8];

    float T1 = 0.f, T2 = 0.f, Zg = 0.f;
    const float* ub = u + ((size_t)(b * 4096 + tg)) * 512 + 4 * q;

    #pragma unroll 2
    for (int kk = 0; kk < 16; ++kk) {
        #pragma unroll
        for (int ii = 0; ii < 2; ++ii) {
            const int i = 2 * kk + ii;   // m = 16*i + 4*q + r
            const unsigned short* wrow = Wbf + (size_t)(16 * i + ln) * 64 + q * 8;
            bf16x8 a0 = *(const bf16x8*)(wrow);
            bf16x8 a1 = *(const bf16x8*)(wrow + 32);
            float4 uv = *(const float4*)(ub + 16 * i);
            const float4 wv = *(const float4*)(wn2 + 16 * i + 4 * q);

            floatx4 acc = 0.0f;
            acc = __builtin_amdgcn_mfma_f32_16x16x32_bf16(a0, xb0, acc, 0, 0, 0);
            acc = __builtin_amdgcn_mfma_f32_16x16x32_bf16(a1, xb1, acc, 0, 0, 0);
            // C/D layout: n = ln (t), m = 16*i + 4*q + r

            float sr[4];
            const float ua[4] = {uv.x, uv.y, uv.z, uv.w};
            const float wa[4] = {wv.x, wv.y, wv.z, wv.w};
            #pragma unroll
            for (int r = 0; r < 4; ++r) {
                float l = fmaf(2.0f, acc[r], -wa[r]);
                float e = __expf(l);
                T1 += e;
                T2 = fmaf(l, e, T2);
                float uu = fmaxf(ua[r], 1e-9f);
                float z = uu - 1.0f;
                float p = fmaf(z, -0.125f, 0.14285715f);
                p = fmaf(z, p, -0.16666667f);
                p = fmaf(z, p, 0.2f);
                p = fmaf(z, p, -0.25f);
                p = fmaf(z, p, 0.33333334f);
                p = fmaf(z, p, -0.5f);
                p = fmaf(z, p, 1.0f);
                float il = (uu > 0.75f) ? (z * p) : __logf(uu);  // log(u) < 0
                float rr = e * __builtin_amdgcn_rcpf(il);        // e^l / log(u)
                float s = (rr * rr) * EXPM36;                    // exp(2l+2g-36)
                Zg += s;
                sr[r] = s;
            }
            *(uint2*)&sbuf[w][ln][16 * ii + 4 * q] = make_uint2(
                f2bf_bits(sr[0]) | (f2bf_bits(sr[1]) << 16),
                f2bf_bits(sr[2]) | (f2bf_bits(sr[3]) << 16));
        }
        // wave-private transpose: drain DS, read B-frag, store coalesced
        __asm__ volatile("s_waitcnt lgkmcnt(0)" ::: "memory");
        uint4 sv = *(const uint4*)&sbuf[w][ln][8 * q];
        *(uint4*)(Sblk + (((size_t)bid * 16 + kk) * 4 + w) * 512 + lane * 8) = sv;
    }

    // per-t reductions: codes for t live in lanes {ln, ln+16, ln+32, ln+48}
    T1 += __shfl_xor(T1, 16); T1 += __shfl_xor(T1, 32);
    T2 += __shfl_xor(T2, 16); T2 += __shfl_xor(T2, 32);
    Zg += __shfl_xor(Zg, 16); Zg += __shfl_xor(Zg, 32);

    // KL(t) = T2/T1 - ln(T1) + ln(M)
    float klw = T2 / T1 - logf(T1) + LOG_M;
    klw += __shfl_xor(klw, 1);  klw += __shfl_xor(klw, 2);
    klw += __shfl_xor(klw, 4);  klw += __shfl_xor(klw, 8);
    klw += __shfl_xor(klw, 16); klw += __shfl_xor(klw, 32);
    if (lane == 0)
        atomicAdd(&kl_sh[((bid * 4 + w) & 15) * 64], 0.25f * klw);

    if (q == 0) invZg[(size_t)b * 4096 + tg] = 1.0f / Zg;
}

// ---------------- K2: GEMM2 + avg_probs ------------------------------------
// grid = 2048, block = 256 (4 waves), same (b,t) mapping as K1.
__global__ __launch_bounds__(256, 4) void vq_qnt(
    const unsigned short* __restrict__ Sblk,
    const unsigned short* __restrict__ WTbf,
    const float* __restrict__ invZg,
    float* __restrict__ out,
    float* __restrict__ avg_sh)
{
    __shared__ float avg_wv[4][512];   // per-wave avg partials (no atomics)

    const int tid  = threadIdx.x;
    const int bid  = blockIdx.x;
    const int b    = bid >> 6;
    const int t0   = (bid & 63) << 6;
    const int w    = tid >> 6;
    const int lane = tid & 63;
    const int ln   = lane & 15;
    const int q    = lane >> 4;
    const int tg   = t0 + 16 * w + ln;

    const float invZ = invZg[(size_t)b * 4096 + tg];

    floatx4 C2[4];
    #pragma unroll
    for (int dt = 0; dt < 4; ++dt) C2[dt] = 0.0f;

    #pragma unroll 4
    for (int kk = 0; kk < 16; ++kk) {
        // B-frag: S[m = 32kk + 8q + j][t = 16w + ln], fully coalesced 16B/lane
        uint4 sv = *(const uint4*)(Sblk + (((size_t)bid * 16 + kk) * 4 + w) * 512 + lane * 8);
        bf16x8 sb = __builtin_bit_cast(bf16x8, sv);

        // avg_probs: p = s * invZ(t), reduce over t (= ln axis) via DPP
        float p0 = bf2f(sv.x & 0xffffu) * invZ;
        float p1 = bf2f(sv.x >> 16)     * invZ;
        float p2 = bf2f(sv.y & 0xffffu) * invZ;
        float p3 = bf2f(sv.y >> 16)     * invZ;
        float p4 = bf2f(sv.z & 0xffffu) * invZ;
        float p5 = bf2f(sv.z >> 16)     * invZ;
        float p6 = bf2f(sv.w & 0xffffu) * invZ;
        float p7 = bf2f(sv.w >> 16)     * invZ;
        p0 = row16_sum(p0); p1 = row16_sum(p1); p2 = row16_sum(p2); p3 = row16_sum(p3);
        p4 = row16_sum(p4); p5 = row16_sum(p5); p6 = row16_sum(p6); p7 = row16_sum(p7);
        if (ln == 0) {
            // each m = 32kk+8q+j touched exactly once per wave: plain stores
            *(float4*)&avg_wv[w][32 * kk + 8 * q]     = make_float4(p0, p1, p2, p3);
            *(float4*)&avg_wv[w][32 * kk + 8 * q + 4] = make_float4(p4, p5, p6, p7);
        }

        #pragma unroll
        for (int dt = 0; dt < 4; ++dt) {
            // A-frag: A[d = 16dt+ln][k = 32kk + q*8+j] = W^T (m-contiguous)
            bf16x8 a = *(const bf16x8*)(WTbf + (size_t)(16 * dt + ln) * 512 + 32 * kk + 8 * q);
            C2[dt] = __builtin_amdgcn_mfma_f32_16x16x32_bf16(a, sb, C2[dt], 0, 0, 0);
        }
    }

    // epilogue: normalize and store quantized; lane holds d = 16dt+4q+r at t
    float* op = out + ((size_t)(b * 4096 + tg)) * 64 + 4 * q;
    #pragma unroll
    for (int dt = 0; dt < 4; ++dt) {
        floatx4 c = C2[dt];
        c[0] *= invZ; c[1] *= invZ; c[2] *= invZ; c[3] *= invZ;
        *(floatx4*)(op + 16 * dt) = c;
    }

    // fold per-wave avg partials, one shadowed global atomic per m
    __syncthreads();
    #pragma unroll
    for (int mm = tid; mm < 512; mm += 256) {
        float s = avg_wv[0][mm] + avg_wv[1][mm] + avg_wv[2][mm] + avg_wv[3][mm];
        atomicAdd(&avg_sh[(bid & 15) * 512 + mm], s);
    }
}

// ---------------- finalize (split path): KL mean + perplexity --------------
__global__ void vq_fin1(const float* __restrict__ avg_sh,
                        const float* __restrict__ kl_sh,
                        float* __restrict__ out)
{
    const int lane = threadIdx.x;   // 64 threads
    float acc = 0.f;
    #pragma unroll
    for (int k = 0; k < 8; ++k) {
        float a = 0.f;
        #pragma unroll
        for (int c = 0; c < 16; ++c) a += avg_sh[c * 512 + lane * 8 + k];
        a *= (1.0f / 131072.0f);
        acc += a * logf(a + 1e-10f);
    }
    float kv = (lane < 16) ? kl_sh[lane * 64] : 0.f;
    acc += __shfl_xor(acc, 1);  acc += __shfl_xor(acc, 2);
    acc += __shfl_xor(acc, 4);  acc += __shfl_xor(acc, 8);
    acc += __shfl_xor(acc, 16); acc += __shfl_xor(acc, 32);
    kv  += __shfl_xor(kv, 1);   kv  += __shfl_xor(kv, 2);
    kv  += __shfl_xor(kv, 4);   kv  += __shfl_xor(kv, 8);
    kv  += __shfl_xor(kv, 16);  kv  += __shfl_xor(kv, 32);
    if (lane == 0) {
        out[8388608] = kv * (1.0f / 32.0f);   // mean over B
        out[8388609] = expf(-acc);
    }
}

// ================== fallback path (verified R1 kernel) ======================
__global__ __launch_bounds__(256, 3) void vq_main(
    const float* __restrict__ x, const float* __restrict__ u,
    const unsigned short* __restrict__ Wbf, const unsigned short* __restrict__ WTbf,
    const float* __restrict__ wn2, float* __restrict__ out,
    float* __restrict__ avg_g, float* __restrict__ kl_g)
{
    __shared__ __align__(16) unsigned short xs[64][72];
    __shared__ __align__(16) unsigned short sbuf[4][16][40];
    __shared__ float avg_lds[512];

    const int tid  = threadIdx.x;
    const int bid  = blockIdx.x;
    const int b    = bid >> 6;
    const int t0   = (bid & 63) << 6;
    const int w    = tid >> 6;
    const int lane = tid & 63;
    const int ln   = lane & 15;
    const int q    = lane >> 4;

    avg_lds[tid]       = 0.0f;
    avg_lds[tid + 256] = 0.0f;

    #pragma unroll
    for (int k2 = 0; k2 < 16; ++k2) {
        int idx = k2 * 256 + tid;
        int d = idx >> 6, t = idx & 63;
        float v = x[((size_t)(b * 64 + d)) * 4096 + (size_t)(t0 + t)];
        xs[t][d] = (unsigned short)f2bf_bits(v);
    }
    __syncthreads();

    const int tg = t0 + 16 * w + ln;

    bf16x8 xb0 = *(const bf16x8*)&xs[16 * w + ln][q * 8];
    bf16x8 xb1 = *(const bf16x8*)&xs[16 * w + ln][32 + q * 8];

    unsigned int spk[64];
    float T1 = 0.f, T2 = 0.f, Zg = 0.f;
    const float* ub = u + ((size_t)(b * 4096 + tg)) * 512 + 4 * q;

    #pragma unroll
    for (int i = 0; i < 32; ++i) {
        const unsigned short* wrow = Wbf + (size_t)(16 * i + ln) * 64 + q * 8;
        bf16x8 a0 = *(const bf16x8*)(wrow);
        bf16x8 a1 = *(const bf16x8*)(wrow + 32);
        float4 uv = *(const float4*)(ub + 16 * i);
        const float4 wv = *(const float4*)(wn2 + 16 * i + 4 * q);

        floatx4 acc = 0.0f;
        acc = __builtin_amdgcn_mfma_f32_16x16x32_bf16(a0, xb0, acc, 0, 0, 0);
        acc = __builtin_amdgcn_mfma_f32_16x16x32_bf16(a1, xb1, acc, 0, 0, 0);

        float sr[4];
        const float ua[4] = {uv.x, uv.y, uv.z, uv.w};
        const float wa[4] = {wv.x, wv.y, wv.z, wv.w};
        #pragma unroll
        for (int r = 0; r < 4; ++r) {
            float l = fmaf(2.0f, acc[r], -wa[r]);
            float e = __expf(l);
            T1 += e;
            T2 = fmaf(l, e, T2);
            float uu = fmaxf(ua[r], 1e-9f);
            float z = uu - 1.0f;
            float p = fmaf(z, -0.125f, 0.14285715f);
            p = fmaf(z, p, -0.16666667f);
            p = fmaf(z, p, 0.2f);
            p = fmaf(z, p, -0.25f);
            p = fmaf(z, p, 0.33333334f);
            p = fmaf(z, p, -0.5f);
            p = fmaf(z, p, 1.0f);
            float il = (uu > 0.75f) ? (z * p) : __logf(uu);
            float rr = e * __builtin_amdgcn_rcpf(il);
            float s = (rr * rr) * EXPM36;
            Zg += s;
            sr[r] = s;
        }
        spk[2 * i]     = f2bf_bits(sr[0]) | (f2bf_bits(sr[1]) << 16);
        spk[2 * i + 1] = f2bf_bits(sr[2]) | (f2bf_bits(sr[3]) << 16);
    }

    T1 += __shfl_xor(T1, 16); T1 += __shfl_xor(T1, 32);
    T2 += __shfl_xor(T2, 16); T2 += __shfl_xor(T2, 32);
    Zg += __shfl_xor(Zg, 16); Zg += __shfl_xor(Zg, 32);

    float klw = T2 / T1 - logf(T1) + LOG_M;
    klw += __shfl_xor(klw, 1);  klw += __shfl_xor(klw, 2);
    klw += __shfl_xor(klw, 4);  klw += __shfl_xor(klw, 8);
    klw += __shfl_xor(klw, 16); klw += __shfl_xor(klw, 32);
    if (lane == 0) atomicAdd(kl_g, 0.25f * klw);

    const float invZ = 1.0f / Zg;

    floatx4 C2[4];
    #pragma unroll
    for (int dt = 0; dt < 4; ++dt) C2[dt] = 0.0f;

    #pragma unroll
    for (int kk = 0; kk < 16; ++kk) {
        #pragma unroll
        for (int ii = 0; ii < 2; ++ii) {
            const int i = 2 * kk + ii;
            uint2 pk;
            pk.x = spk[2 * i];
            pk.y = spk[2 * i + 1];
            *(uint2*)&sbuf[w][ln][16 * ii + 4 * q] = pk;
            float v0 = bf2f(pk.x & 0xffffu) * invZ;
            float v1 = bf2f(pk.x >> 16)     * invZ;
            float v2 = bf2f(pk.y & 0xffffu) * invZ;
            float v3 = bf2f(pk.y >> 16)     * invZ;
            v0 += __shfl_xor(v0,1); v0 += __shfl_xor(v0,2); v0 += __shfl_xor(v0,4); v0 += __shfl_xor(v0,8);
            v1 += __shfl_xor(v1,1); v1 += __shfl_xor(v1,2); v1 += __shfl_xor(v1,4); v1 += __shfl_xor(v1,8);
            v2 += __shfl_xor(v2,1); v2 += __shfl_xor(v2,2); v2 += __shfl_xor(v2,4); v2 += __shfl_xor(v2,8);
            v3 += __shfl_xor(v3,1); v3 += __shfl_xor(v3,2); v3 += __shfl_xor(v3,4); v3 += __shfl_xor(v3,8);
            if (ln == 0) {
                atomicAdd(&avg_lds[16*i + 4*q + 0], v0);
                atomicAdd(&avg_lds[16*i + 4*q + 1], v1);
                atomicAdd(&avg_lds[16*i + 4*q + 2], v2);
                atomicAdd(&avg_lds[16*i + 4*q + 3], v3);
            }
        }
        __asm__ volatile("s_waitcnt lgkmcnt(0)" ::: "memory");
        bf16x8 sb = *(const bf16x8*)&sbuf[w][ln][8 * q];
        #pragma unroll
        for (int dt = 0; dt < 4; ++dt) {
            bf16x8 a = *(const bf16x8*)(WTbf + (size_t)(16 * dt + ln) * 512 + 32 * kk + 8 * q);
            C2[dt] = __builtin_amdgcn_mfma_f32_16x16x32_bf16(a, sb, C2[dt], 0, 0, 0);
        }
    }

    float* op = out + ((size_t)(b * 4096 + tg)) * 64 + 4 * q;
    #pragma unroll
    for (int dt = 0; dt < 4; ++dt) {
        floatx4 c = C2[dt];
        c[0] *= invZ; c[1] *= invZ; c[2] *= invZ; c[3] *= invZ;
        *(floatx4*)(op + 16 * dt) = c;
    }

    __syncthreads();
    atomicAdd(&avg_g[tid],       avg_lds[tid]);
    atomicAdd(&avg_g[tid + 256], avg_lds[tid + 256]);
}

__global__ void vq_fin0(const float* __restrict__ avg_g, const float* __restrict__ kl_g,
                        float* __restrict__ out)
{
    const int lane = threadIdx.x;   // 64 threads
    float acc = 0.f;
    #pragma unroll
    for (int k = 0; k < 8; ++k) {
        float a = avg_g[lane * 8 + k] * (1.0f / 131072.0f);
        acc += a * logf(a + 1e-10f);
    }
    acc += __shfl_xor(acc, 1);  acc += __shfl_xor(acc, 2);
    acc += __shfl_xor(acc, 4);  acc += __shfl_xor(acc, 8);
    acc += __shfl_xor(acc, 16); acc += __shfl_xor(acc, 32);
    if (lane == 0) {
        out[8388608] = kl_g[0] * (1.0f / 32.0f);
        out[8388609] = expf(-acc);
    }
}

// ================== host launch ============================================
extern "C" void kernel_launch(void* const* d_in, const int* in_sizes, int n_in,
                              void* d_out, int out_size, void* d_ws, size_t ws_size,
                              hipStream_t stream)
{
    const float* x = (const float*)d_in[0];   // (32, 64, 4096)
    const float* u = (const float*)d_in[1];   // (32, 4096, 512)
    const float* W = (const float*)d_in[2];   // (512, 64)
    float* out = (float*)d_out;

    char* ws = (char*)d_ws;
    unsigned short* Wbf  = (unsigned short*)(ws);            // 65536 B
    unsigned short* WTbf = (unsigned short*)(ws + 65536);    // 65536 B
    float* wn2   = (float*)(ws + 131072);                    // 2048 B

    const size_t NEED = 1048576ull + 134217728ull;           // Sblk @ 1MiB

    if (ws_size >= NEED) {
        // ---- split path ----
        float* avg_sh = (float*)(ws + 133120);               // 16*512*4 = 32768 B
        float* kl_sh  = (float*)(ws + 165888);               // 16*64*4  = 4096 B
        float* invZg  = (float*)(ws + 169984);               // 524288 B
        unsigned short* Sblk = (unsigned short*)(ws + 1048576);  // 128 MiB

        vq_prep<<<dim3(2),    dim3(256), 0, stream>>>(W, Wbf, WTbf, wn2,
                                                      avg_sh, kl_sh, 1);
        vq_samp<<<dim3(2048), dim3(256), 0, stream>>>(x, u, Wbf, wn2,
                                                      Sblk, invZg, kl_sh);
        vq_qnt <<<dim3(2048), dim3(256), 0, stream>>>(Sblk, WTbf, invZg,
                                                      out, avg_sh);
        vq_fin1<<<dim3(1),    dim3(64),  0, stream>>>(avg_sh, kl_sh, out);
    } else {
        // ---- fallback: verified R1 single-kernel path ----
        float* avg_g = (float*)(ws + 133120);                // 2048 B
        float* kl_g  = (float*)(ws + 135168);                // 4 B
        (void)hipMemsetAsync(ws + 133120, 0, 2048 + 64, stream);
        vq_prep<<<dim3(2),    dim3(256), 0, stream>>>(W, Wbf, WTbf, wn2,
                                                      avg_g, kl_g, 0);
        vq_main<<<dim3(2048), dim3(256), 0, stream>>>(x, u, Wbf, WTbf, wn2,
                                                      out, avg_g, kl_g);
        vq_fin0<<<dim3(1),    dim3(64),  0, stream>>>(avg_g, kl_g, out);
    }
}

// Round 4
// 500.789 us; speedup vs baseline: 1.1383x; 1.0066x over previous
//
#include <hip/hip_runtime.h>
#include <hip/hip_bf16.h>
#include <math.h>

// VQEmbeddingGSSoft fused kernel for MI355X (gfx950).
// B=32, C=D=64, T=4096, M=512, temperature=0.5.
// Outputs: quantized (B,T,64) [8388608 floats], KL [1], perplexity [1].
//
// R4 = R3 resubmission (R3 bench was an infra failure: "container failed
// twice", no counters; source re-audited for OOB/sync/LDS-size faults, none
// found). Structure: single fused kernel, waves split over M (not T).
//   Block = 256 thr (4 waves) owns 16 t-values x all 512 codes.
//   Wave w owns m in [128w, 128w+128): GEMM1 = 8 MFMA iters, spk = 16 regs
//   (vs 64 in R1 -> no occupancy collapse). Z/T1/T2 via cross-wave LDS
//   reduction (invZ is block-local -> S never leaves the CU; R2's 268 MB
//   S round-trip eliminated). GEMM2 is K-split: per-wave K=128 partial C2,
//   reduced through padded LDS. avg_probs via DPP row-reductions, written
//   once per m (no LDS atomics), 32-way shadowed global atomics.
//
// Algebra (unchanged, verified R0-R2):
//  - softmax shift-invariance: l_m = 2*x.w_m - ||w_m||^2
//  - s = (e^l / log u)^2 * e^-36  == exp(2l + 2g - 36), g = -log(-log u)
//  - KL(t) = T2/T1 - ln(T1) + ln(M);  normalization deferred to epilogue.

#define LOG_M   6.2383246250395075f   // ln(512)
#define EXPM36  2.3195228e-16f        // e^-36

typedef __attribute__((ext_vector_type(8))) __bf16 bf16x8;
typedef __attribute__((ext_vector_type(4))) float  floatx4;

__device__ __forceinline__ unsigned int f2bf_bits(float f) {
    unsigned int b = __builtin_bit_cast(unsigned int, f);
    return (b + 0x7fffu + ((b >> 16) & 1u)) >> 16;   // RNE bf16
}
__device__ __forceinline__ float bf2f(unsigned int bits16) {
    return __builtin_bit_cast(float, bits16 << 16);
}
// DPP add: v += lane-permuted v (VALU pipe, no DS traffic)
template <int CTRL>
__device__ __forceinline__ float dpp_add(float v) {
    int t = __builtin_amdgcn_update_dpp(0, __builtin_bit_cast(int, v),
                                        CTRL, 0xF, 0xF, true);
    return v + __builtin_bit_cast(float, t);
}
// full reduction over the 16-lane row (ln axis): xor1, xor2, ror4, ror8
__device__ __forceinline__ float row16_sum(float v) {
    v = dpp_add<0xB1>(v);    // quad_perm [1,0,3,2]  (xor 1)
    v = dpp_add<0x4E>(v);    // quad_perm [2,3,0,1]  (xor 2)
    v = dpp_add<0x124>(v);   // row_ror:4
    v = dpp_add<0x128>(v);   // row_ror:8
    return v;
}

// ---------------- prep: W fp32 -> bf16 (row-major + transposed) + ||w||^2 ----
// Also zeroes the shadow accumulators (ws is poisoned 0xAA before launch).
__global__ void vq_prep(const float* __restrict__ W,
                        unsigned short* __restrict__ Wbf,
                        unsigned short* __restrict__ WTbf,
                        float* __restrict__ wn2,
                        float* __restrict__ avg_sh,   // [32][512]
                        float* __restrict__ kl_sh)    // [64]
{
    const int m = blockIdx.x * 256 + threadIdx.x;   // 0..511
    float acc = 0.f;
    #pragma unroll 8
    for (int d = 0; d < 64; ++d) {
        float v = W[m * 64 + d];
        acc = fmaf(v, v, acc);
        unsigned short h = (unsigned short)f2bf_bits(v);
        Wbf[m * 64 + d]  = h;
        WTbf[d * 512 + m] = h;
    }
    wn2[m] = acc;
    #pragma unroll
    for (int j = 0; j < 32; ++j) avg_sh[j * 512 + m] = 0.f;
    if (m < 64) kl_sh[m] = 0.f;
}

// ---------------- fused main kernel ----------------------------------------
// grid = 8192 (32 b x 256 t-tiles of 16), block = 256 (4 waves).
// Wave w: m in [128w, 128w+128) for all 16 t's of the tile.
__global__ __launch_bounds__(256, 4) void vq_fused(
    const float* __restrict__ x, const float* __restrict__ u,
    const unsigned short* __restrict__ Wbf, const unsigned short* __restrict__ WTbf,
    const float* __restrict__ wn2, float* __restrict__ out,
    float* __restrict__ avg_sh, float* __restrict__ kl_sh)
{
    __shared__ __align__(16) unsigned short xs[16][72];      // x tile [t][d], padded
    __shared__ __align__(16) unsigned short sbuf[4][16][40]; // per-wave transpose buf
    __shared__ float red[4][3][16];                          // T1/T2/Zg partials
    __shared__ __align__(16) float c2r[4][64][20];           // C2 K-split partials (padded)
    __shared__ float avg_lds[512];

    const int tid  = threadIdx.x;
    const int bid  = blockIdx.x;
    const int b    = bid >> 8;
    const int t0   = (bid & 255) << 4;
    const int w    = tid >> 6;
    const int lane = tid & 63;
    const int ln   = lane & 15;   // t within tile
    const int q    = lane >> 4;   // quad
    const int m0   = 128 * w;     // this wave's m base

    // stage x tile: xs[t][d] = bf16(x[b][d][t0+t])
    #pragma unroll
    for (int k2 = 0; k2 < 4; ++k2) {
        int idx = k2 * 256 + tid;       // 0..1023
        int d = idx >> 4, t = idx & 15;
        float v = x[((size_t)(b * 64 + d)) * 4096 + (size_t)(t0 + t)];
        xs[t][d] = (unsigned short)f2bf_bits(v);
    }
    __syncthreads();

    const int tg = t0 + ln;   // this lane's global t

    // B-frag of GEMM1 (x tile): B[k=d=q*8+j][n=t=ln]
    bf16x8 xb0 = *(const bf16x8*)&xs[ln][q * 8];
    bf16x8 xb1 = *(const bf16x8*)&xs[ln][32 + q * 8];

    // ---- GEMM1 + gumbel: 8 iterations over this wave's 128 m's ----
    unsigned int spk[16];   // 32 samples/lane, packed 2x bf16 (unnormalized)
    float T1 = 0.f, T2 = 0.f, Zg = 0.f;
    const float* ub = u + ((size_t)(b * 4096 + tg)) * 512 + m0 + 4 * q;

    #pragma unroll   // FULL unroll: spk indices compile-time (stay in VGPRs)
    for (int i = 0; i < 8; ++i) {
        // A-frag: W rows m = m0 + 16i + ln, k = d = q*8+j
        const unsigned short* wrow = Wbf + (size_t)(m0 + 16 * i + ln) * 64 + q * 8;
        bf16x8 a0 = *(const bf16x8*)(wrow);
        bf16x8 a1 = *(const bf16x8*)(wrow + 32);
        float4 uv = *(const float4*)(ub + 16 * i);
        const float4 wv = *(const float4*)(wn2 + m0 + 16 * i + 4 * q);

        floatx4 acc = 0.0f;
        acc = __builtin_amdgcn_mfma_f32_16x16x32_bf16(a0, xb0, acc, 0, 0, 0);
        acc = __builtin_amdgcn_mfma_f32_16x16x32_bf16(a1, xb1, acc, 0, 0, 0);
        // C/D layout: n = ln (t), m = m0 + 16i + 4q + r

        float sr[4];
        const float ua[4] = {uv.x, uv.y, uv.z, uv.w};
        const float wa[4] = {wv.x, wv.y, wv.z, wv.w};
        #pragma unroll
        for (int r = 0; r < 4; ++r) {
            float l = fmaf(2.0f, acc[r], -wa[r]);
            float e = __expf(l);
            T1 += e;
            T2 = fmaf(l, e, T2);
            float uu = fmaxf(ua[r], 1e-9f);
            // inner log: accurate near 1 via log1p poly, HW log otherwise
            float z = uu - 1.0f;
            float p = fmaf(z, -0.125f, 0.14285715f);
            p = fmaf(z, p, -0.16666667f);
            p = fmaf(z, p, 0.2f);
            p = fmaf(z, p, -0.25f);
            p = fmaf(z, p, 0.33333334f);
            p = fmaf(z, p, -0.5f);
            p = fmaf(z, p, 1.0f);
            float il = (uu > 0.75f) ? (z * p) : __logf(uu);   // log(u) < 0
            float rr = e * __builtin_amdgcn_rcpf(il);          // e^l / log(u)
            float s = (rr * rr) * EXPM36;                      // exp(2l + 2g - 36)
            Zg += s;
            sr[r] = s;
        }
        spk[2 * i]     = f2bf_bits(sr[0]) | (f2bf_bits(sr[1]) << 16);
        spk[2 * i + 1] = f2bf_bits(sr[2]) | (f2bf_bits(sr[3]) << 16);
    }

    // per-wave per-t partials: fold the q axis (lanes {ln, ln+16, ln+32, ln+48})
    T1 += __shfl_xor(T1, 16); T1 += __shfl_xor(T1, 32);
    T2 += __shfl_xor(T2, 16); T2 += __shfl_xor(T2, 32);
    Zg += __shfl_xor(Zg, 16); Zg += __shfl_xor(Zg, 32);
    if (q == 0) {
        red[w][0][ln] = T1;
        red[w][1][ln] = T2;
        red[w][2][ln] = Zg;
    }
    __syncthreads();

    const float T1t = red[0][0][ln] + red[1][0][ln] + red[2][0][ln] + red[3][0][ln];
    const float T2t = red[0][1][ln] + red[1][1][ln] + red[2][1][ln] + red[3][1][ln];
    const float Zgt = red[0][2][ln] + red[1][2][ln] + red[2][2][ln] + red[3][2][ln];
    const float invZ = 1.0f / Zgt;

    // KL: one wave computes it; sum over 64 lanes = 4x sum over the 16 t's
    if (w == 0) {
        float klw = T2t / T1t - logf(T1t) + LOG_M;
        klw += __shfl_xor(klw, 1);  klw += __shfl_xor(klw, 2);
        klw += __shfl_xor(klw, 4);  klw += __shfl_xor(klw, 8);
        klw += __shfl_xor(klw, 16); klw += __shfl_xor(klw, 32);
        if (lane == 0) atomicAdd(&kl_sh[bid & 63], 0.25f * klw);
    }

    // ---- GEMM2 (K-split): this wave's K=128 partial of Q^T = W^T @ S_un ----
    floatx4 C2[4];
    #pragma unroll
    for (int dt = 0; dt < 4; ++dt) C2[dt] = 0.0f;

    #pragma unroll
    for (int kk = 0; kk < 4; ++kk) {
        #pragma unroll
        for (int ii = 0; ii < 2; ++ii) {
            const int i = 2 * kk + ii;   // local m chunk: 16i + 4q + r
            *(uint2*)&sbuf[w][ln][16 * ii + 4 * q] =
                make_uint2(spk[2 * i], spk[2 * i + 1]);
        }
        // cross-lane LDS RAW within the wave: drain DS queue before frag read
        __asm__ volatile("s_waitcnt lgkmcnt(0)" ::: "memory");
        uint4 sv = *(const uint4*)&sbuf[w][ln][8 * q];
        bf16x8 sb = __builtin_bit_cast(bf16x8, sv);

        // avg_probs: p = s * invZ(t), reduce over t (ln axis) via DPP;
        // each m = m0 + 32kk + 8q + j is produced by exactly one lane-group
        float p0 = bf2f(sv.x & 0xffffu) * invZ;
        float p1 = bf2f(sv.x >> 16)     * invZ;
        float p2 = bf2f(sv.y & 0xffffu) * invZ;
        float p3 = bf2f(sv.y >> 16)     * invZ;
        float p4 = bf2f(sv.z & 0xffffu) * invZ;
        float p5 = bf2f(sv.z >> 16)     * invZ;
        float p6 = bf2f(sv.w & 0xffffu) * invZ;
        float p7 = bf2f(sv.w >> 16)     * invZ;
        p0 = row16_sum(p0); p1 = row16_sum(p1); p2 = row16_sum(p2); p3 = row16_sum(p3);
        p4 = row16_sum(p4); p5 = row16_sum(p5); p6 = row16_sum(p6); p7 = row16_sum(p7);
        if (ln == 0) {
            *(float4*)&avg_lds[m0 + 32 * kk + 8 * q]     = make_float4(p0, p1, p2, p3);
            *(float4*)&avg_lds[m0 + 32 * kk + 8 * q + 4] = make_float4(p4, p5, p6, p7);
        }

        #pragma unroll
        for (int dt = 0; dt < 4; ++dt) {
            // A-frag: A[d = 16dt+ln][k = m0 + 32kk + q*8+j] = W^T (m-contiguous)
            bf16x8 a = *(const bf16x8*)(WTbf + (size_t)(16 * dt + ln) * 512
                                        + m0 + 32 * kk + 8 * q);
            C2[dt] = __builtin_amdgcn_mfma_f32_16x16x32_bf16(a, sb, C2[dt], 0, 0, 0);
        }
    }

    // ---- cross-wave K reduction of C2 through LDS ----
    #pragma unroll
    for (int dt = 0; dt < 4; ++dt)
        *(floatx4*)&c2r[w][lane][4 * dt] = C2[dt];
    __syncthreads();   // also publishes avg_lds

    // wave w finalizes dt = w: element (d = 16w + 4q + r, t = ln)
    floatx4 cf = *(const floatx4*)&c2r[0][lane][4 * w];
    {
        floatx4 c1 = *(const floatx4*)&c2r[1][lane][4 * w];
        floatx4 c2 = *(const floatx4*)&c2r[2][lane][4 * w];
        floatx4 c3 = *(const floatx4*)&c2r[3][lane][4 * w];
        #pragma unroll
        for (int r = 0; r < 4; ++r)
            cf[r] = (cf[r] + c1[r] + c2[r] + c3[r]) * invZ;
    }
    *(floatx4*)(out + ((size_t)(b * 4096 + tg)) * 64 + 16 * w + 4 * q) = cf;

    // avg_probs: one shadowed global atomic per m
    atomicAdd(&avg_sh[(bid & 31) * 512 + tid],       avg_lds[tid]);
    atomicAdd(&avg_sh[(bid & 31) * 512 + tid + 256], avg_lds[tid + 256]);
}

// ---------------- finalize: KL mean + perplexity ----------------
__global__ void vq_fin(const float* __restrict__ avg_sh,
                       const float* __restrict__ kl_sh,
                       float* __restrict__ out)
{
    const int lane = threadIdx.x;   // 64 threads
    float acc = 0.f;
    #pragma unroll
    for (int k = 0; k < 8; ++k) {
        float a = 0.f;
        #pragma unroll
        for (int c = 0; c < 32; ++c) a += avg_sh[c * 512 + lane * 8 + k];
        a *= (1.0f / 131072.0f);
        acc += a * logf(a + 1e-10f);
    }
    float kv = kl_sh[lane];
    acc += __shfl_xor(acc, 1);  acc += __shfl_xor(acc, 2);
    acc += __shfl_xor(acc, 4);  acc += __shfl_xor(acc, 8);
    acc += __shfl_xor(acc, 16); acc += __shfl_xor(acc, 32);
    kv  += __shfl_xor(kv, 1);   kv  += __shfl_xor(kv, 2);
    kv  += __shfl_xor(kv, 4);   kv  += __shfl_xor(kv, 8);
    kv  += __shfl_xor(kv, 16);  kv  += __shfl_xor(kv, 32);
    if (lane == 0) {
        out[8388608] = kv * (1.0f / 32.0f);   // mean over B
        out[8388609] = expf(-acc);
    }
}

// ================== host launch ============================================
extern "C" void kernel_launch(void* const* d_in, const int* in_sizes, int n_in,
                              void* d_out, int out_size, void* d_ws, size_t ws_size,
                              hipStream_t stream)
{
    const float* x = (const float*)d_in[0];   // (32, 64, 4096)
    const float* u = (const float*)d_in[1];   // (32, 4096, 512)
    const float* W = (const float*)d_in[2];   // (512, 64)
    float* out = (float*)d_out;

    char* ws = (char*)d_ws;
    unsigned short* Wbf  = (unsigned short*)(ws);            // 65536 B
    unsigned short* WTbf = (unsigned short*)(ws + 65536);    // 65536 B
    float* wn2    = (float*)(ws + 131072);                   // 2048 B
    float* avg_sh = (float*)(ws + 133120);                   // 32*512*4 = 65536 B
    float* kl_sh  = (float*)(ws + 198656);                   // 64*4 = 256 B

    vq_prep <<<dim3(2),    dim3(256), 0, stream>>>(W, Wbf, WTbf, wn2, avg_sh, kl_sh);
    vq_fused<<<dim3(8192), dim3(256), 0, stream>>>(x, u, Wbf, WTbf, wn2,
                                                   out, avg_sh, kl_sh);
    vq_fin  <<<dim3(1),    dim3(64),  0, stream>>>(avg_sh, kl_sh, out);
}